// Round 14
// baseline (334.283 us; speedup 1.0000x reference)
//
#include <hip/hip_runtime.h>

typedef __bf16 bf8 __attribute__((ext_vector_type(8)));
typedef float f4 __attribute__((ext_vector_type(4)));
typedef unsigned short us4 __attribute__((ext_vector_type(4)));
typedef unsigned int u32x4 __attribute__((ext_vector_type(4)));

#define MFMA16(a,b,c) __builtin_amdgcn_mfma_f32_16x16x32_bf16((a),(b),(c),0,0,0)

#define BLOCK 512
#define HBLOCK 1024
#define CH 16384

__device__ __forceinline__ unsigned short f2bfu(float f){
  __bf16 h = (__bf16)f;
  union { __bf16 b; unsigned short u; } v; v.b = h; return v.u;
}
__device__ __forceinline__ float ubfu(unsigned int u16){
  union { unsigned int i; float f; } v; v.i = u16 << 16; return v.f;
}
__device__ __forceinline__ float u2f(unsigned int u){
  union { unsigned int i; float f; } v; v.i = u; return v.f;
}

// tau: k-slot -> logical row, absorbing the C->B register relayout into weight
// staging. C regs of lane(q,m) hold rows {16t+4q+r}; B-frags need rows
// {8q+j}u{32+8q+j}. tau maps B slot k=(f,q,j) -> C position 32f+16(j>>2)+4q+(j&3).
__device__ __forceinline__ int tauk(int i){
  return ((i >> 5) << 5) | (((i & 7) >> 2) << 4) | (((i >> 3) & 3) << 2) | (i & 3);
}

// LDS layout (ushort element offsets) — WEIGHTS ONLY, no activations.
#define OFF_W1   0       // 32->64 identity : 2048
#define OFF_W2   2048    // 64->64 tau : 4096
#define OFF_W3C  6144    // 64->64 fused (w3@cw1), tau : 4096
#define OFF_CW2  10240   // tau : 4096
#define OFF_CW3  14336   // tau : 4096
#define OFF_CW4  18432   // 64->3 zero-padded, tau : 1024
#define OFF_W3C0 19456   // w3 column 0, tau-permuted : 72
#define SMEM_US  19528   // 39056 B

// bias offsets (bf16 shorts) — identity (outputs stay in logical order)
#define NB_B1  0
#define NB_B2  64
#define NB_BC  128
#define NB_CB2 192
#define NB_CB3 256
#define NB_CB4 320
#define NB_B3S 323

template<int FIN,int FOUT,int KS,int MT,int PERM>
__device__ __forceinline__ void stage_w(const float* w, unsigned short* dst){
  const int total = KS*MT*512;
  for (int e = threadIdx.x; e < total; e += BLOCK){
    int chunk = e >> 9;
    int s = chunk / MT, t = chunk % MT;
    int le = e & 511;
    int lane = le >> 3, j = le & 7;
    int q = lane >> 4, m = lane & 15;
    int i = s*32 + q*8 + j;
    int o = t*16 + m;
    int il = PERM ? tauk(i) : i;
    dst[e] = (i < FIN && o < FOUT) ? f2bfu(w[il*FOUT + o]) : (unsigned short)0;
  }
}

// W3C = w3@cw1 staged with tau on the k index.
__device__ __forceinline__ void stage_w3c(const float* w3, const float* cw1,
                                          unsigned short* dst){
  for (int e = threadIdx.x; e < 4096; e += BLOCK){
    int chunk = e >> 9;
    int s = chunk >> 2, t = chunk & 3;
    int le = e & 511;
    int lane = le >> 3, j = le & 7;
    int q = lane >> 4, m = lane & 15;
    int i = tauk(s*32 + q*8 + j);
    int o = t*16 + m;
    float sum = 0.f;
#pragma unroll
    for (int u = 0; u < 16; ++u) sum = fmaf(w3[i*16+u], cw1[u*64+o], sum);
    dst[e] = f2bfu(sum);
  }
}

#define STAGE_ALL()                                                          \
  stage_w<32,64,1,4,0>(w1,  smem+OFF_W1);                                    \
  stage_w<64,64,2,4,1>(w2,  smem+OFF_W2);                                    \
  stage_w<64,64,2,4,1>(cw2, smem+OFF_CW2);                                   \
  stage_w<64,64,2,4,1>(cw3, smem+OFF_CW3);                                   \
  stage_w<64, 3,2,1,1>(cw4, smem+OFF_CW4);                                   \
  stage_w3c(w3, cw1, smem+OFF_W3C);                                          \
  {                                                                          \
    int t = threadIdx.x;                                                     \
    if (t < 64){                                                             \
      sbias[NB_B1 +t] = f2bfu(b1[t]);                                        \
      sbias[NB_B2 +t] = f2bfu(b2[t]);                                        \
      sbias[NB_CB2+t] = f2bfu(cb2[t]);                                       \
      sbias[NB_CB3+t] = f2bfu(cb3[t]);                                       \
      smem[OFF_W3C0+t] = f2bfu(w3[tauk(t)*16]);                              \
      float bcv = cb1[t];                                                    \
      _Pragma("unroll")                                                      \
      for (int j = 0; j < 16; ++j) bcv = fmaf(b3[j], cw1[j*64+t], bcv);      \
      sbias[NB_BC+t] = f2bfu(bcv);                                           \
    }                                                                        \
    if (t >= 64 && t < 72) smem[OFF_W3C0+t] = 0;                             \
    if (t < 3)  sbias[NB_CB4+t] = f2bfu(cb4[t]);                             \
    if (t == 0) sbias[NB_B3S]   = f2bfu(b3[0]);                              \
  }

// relu + cvt + pack C-regs directly into next-layer B-frags (tau absorbed).
__device__ __forceinline__ void pack2(const f4* acc, bf8& b0, bf8& b1){
#pragma unroll
  for (int t = 0; t < 4; ++t)
#pragma unroll
    for (int r = 0; r < 4; ++r){
      float v = fmaxf(acc[t][r], 0.f);
      if (t < 2) b0[t*4+r] = (__bf16)v; else b1[(t-2)*4+r] = (__bf16)v;
    }
}

// 64->64 layer for TWO tiles sharing each A-fragment read. In/out: B-frags.
__device__ __forceinline__ void layer64_2(const unsigned short* wlds, const unsigned short* sb,
                                          int lane, int q,
                                          bf8& x0b0, bf8& x0b1, bf8& x1b0, bf8& x1b1){
  f4 a0[4], a1[4];
#pragma unroll
  for (int t = 0; t < 4; ++t){
    us4 bb = *(const us4*)(sb + t*16 + q*4);
    f4 c = {ubfu(bb[0]), ubfu(bb[1]), ubfu(bb[2]), ubfu(bb[3])};
    a0[t] = c; a1[t] = c;
  }
#pragma unroll
  for (int t = 0; t < 4; ++t){
    bf8 af0 = *(const bf8*)(wlds + ((0*4+t)*64+lane)*8);
    a0[t] = MFMA16(af0, x0b0, a0[t]);
    a1[t] = MFMA16(af0, x1b0, a1[t]);
    bf8 af1 = *(const bf8*)(wlds + ((1*4+t)*64+lane)*8);
    a0[t] = MFMA16(af1, x0b1, a0[t]);
    a1[t] = MFMA16(af1, x1b1, a1[t]);
  }
  pack2(a0, x0b0, x0b1);
  pack2(a1, x1b0, x1b1);
}

// L1 (32->64) for two tiles from feat-frags (identity k order).
__device__ __forceinline__ void layerL1_2(const unsigned short* smem, const unsigned short* sbias,
                                          bf8 f0, bf8 f1, int lane, int q,
                                          bf8& x0b0, bf8& x0b1, bf8& x1b0, bf8& x1b1){
  f4 a0[4], a1[4];
#pragma unroll
  for (int t = 0; t < 4; ++t){
    us4 bb = *(const us4*)(sbias + NB_B1 + t*16 + q*4);
    f4 c = {ubfu(bb[0]), ubfu(bb[1]), ubfu(bb[2]), ubfu(bb[3])};
    bf8 af = *(const bf8*)(smem + OFF_W1 + (t*64+lane)*8);
    a0[t] = MFMA16(af, f0, c);
    a1[t] = MFMA16(af, f1, c);
  }
  pack2(a0, x0b0, x0b1);
  pack2(a1, x1b0, x1b1);
}

// sigma head for two tiles (read-only on frags).
__device__ __forceinline__ void sigma2(const unsigned short* smem, float b3f, int lane, int q,
                                       bf8 x0b0, bf8 x0b1, bf8 x1b0, bf8 x1b1,
                                       float* out, int gp0, int gp1, int nB){
  bf8 wa0 = *(const bf8*)(smem + OFF_W3C0 + q*8);
  bf8 wa1 = *(const bf8*)(smem + OFF_W3C0 + 32 + q*8);
  f4 c0 = {b3f, b3f, b3f, b3f};
  f4 c1 = c0;
  c0 = MFMA16(wa0, x0b0, c0);  c1 = MFMA16(wa0, x1b0, c1);
  c0 = MFMA16(wa1, x0b1, c0);  c1 = MFMA16(wa1, x1b1, c1);
  if (q == 0){
    if (gp0 < nB) out[gp0] = expf(c0[0]);
    if (gp1 < nB) out[gp1] = expf(c1[0]);
  }
}

// C4 head (64->3 + sigmoid) for two tiles.
__device__ __forceinline__ void c4_2(const unsigned short* smem, const unsigned short* sbias,
                                     int lane, int q,
                                     bf8 x0b0, bf8 x0b1, bf8 x1b0, bf8 x1b1,
                                     float* out, int gp0, int gp1, int nB){
  bf8 wa0 = *(const bf8*)(smem + OFF_CW4 + lane*8);
  bf8 wa1 = *(const bf8*)(smem + OFF_CW4 + (64+lane)*8);
  f4 c0 = {0.f,0.f,0.f,0.f};
  f4 c1 = c0;
  c0 = MFMA16(wa0, x0b0, c0);  c1 = MFMA16(wa0, x1b0, c1);
  c0 = MFMA16(wa1, x0b1, c0);  c1 = MFMA16(wa1, x1b1, c1);
  if (q == 0){
#pragma unroll
    for (int r = 0; r < 3; ++r){
      float br = ubfu(sbias[NB_CB4 + r]);
      if (gp0 < nB) out[nB + gp0*3 + r] = 1.f/(1.f + expf(-(c0[r] + br)));
      if (gp1 < nB) out[nB + gp1*3 + r] = 1.f/(1.f + expf(-(c1[r] + br)));
    }
  }
}

// ---------------------------------------------------------------------------
// Phase A: per-level hash encode, full table in LDS, 2-point ILP.
// ---------------------------------------------------------------------------
struct HPt { unsigned idx[8]; float w[8]; };

__device__ __forceinline__ void hprep(const float* __restrict__ xin, int p,
                                      int res, float sc, bool dense, HPt& h){
  const float px = xin[p*3+0], py = xin[p*3+1], pz = xin[p*3+2];
  const float xs=(px+1.f)*sc, ys=(py+1.f)*sc, zs=(pz+1.f)*sc;
  const float fx=floorf(xs), fy=floorf(ys), fz=floorf(zs);
  const float wx=xs-fx, wy=ys-fy, wz=zs-fz;
  int ix0=min(max((int)fx,0),res-1);
  int iy0=min(max((int)fy,0),res-1);
  int iz0=min(max((int)fz,0),res-1);
  int ix1=min(ix0+1,res-1), iy1=min(iy0+1,res-1), iz1=min(iz0+1,res-1);
  unsigned X0,X1,Y0,Y1,Z0,Z1;
  if (dense){
    X0=(unsigned)ix0;            X1=(unsigned)ix1;
    Y0=(unsigned)(res*iy0);      Y1=(unsigned)(res*iy1);
    Z0=(unsigned)(res*res*iz0);  Z1=(unsigned)(res*res*iz1);
  } else {
    X0=(unsigned)ix0;                 X1=(unsigned)ix1;
    Y0=(unsigned)iy0*2654435761u;     Y1=(unsigned)iy1*2654435761u;
    Z0=(unsigned)iz0*805459861u;      Z1=(unsigned)iz1*805459861u;
  }
  const float wx0=1.f-wx, wy0=1.f-wy, wz0=1.f-wz;
  const float wxy0=wx0*wy0, wxy1=wx*wy0, wxy2=wx0*wy, wxy3=wx*wy;
#pragma unroll
  for (int c = 0; c < 8; ++c){
    unsigned xc = (c&1)?X1:X0;
    unsigned yc = (c&2)?Y1:Y0;
    unsigned zc = (c&4)?Z1:Z0;
    h.idx[c] = dense ? (xc+yc+zc) : ((xc^yc^zc)&16383u);
    float wxy = (c&2) ? ((c&1)?wxy3:wxy2) : ((c&1)?wxy1:wxy0);
    h.w[c] = wxy * ((c&4)?wz:wz0);
  }
}

__device__ __forceinline__ unsigned hgather(const unsigned* stab, const HPt& h){
  float f0=0.f, f1=0.f;
#pragma unroll
  for (int c = 0; c < 8; ++c){
    unsigned tv = stab[h.idx[c]];
    f0 = fmaf(h.w[c], u2f(tv << 16), f0);
    f1 = fmaf(h.w[c], u2f(tv & 0xffff0000u), f1);
  }
  return ((unsigned)f2bfu(f1) << 16) | (unsigned)f2bfu(f0);
}

__global__ __launch_bounds__(HBLOCK) void hash_phase(
    const float* __restrict__ xin, const float* __restrict__ tab,
    unsigned int* __restrict__ feat, int nB)
{
  __shared__ unsigned int stab[16384];
  const int lvl = blockIdx.y;
  {
    const float2* t2 = (const float2*)tab + (lvl<<14);
    for (int e = threadIdx.x; e < 16384; e += HBLOCK){
      float2 v = t2[e];
      stab[e] = ((unsigned)f2bfu(v.y) << 16) | (unsigned)f2bfu(v.x);
    }
  }
  __syncthreads();

  const int R[16] = {16,20,25,32,40,50,64,80,101,128,161,203,256,322,406,512};
  const int res = R[lvl];
  const float sc = 0.5f*(float)(res-1);
  const bool dense = (lvl < 3);
  unsigned int* fout = feat + (size_t)lvl * (size_t)nB;

  int pend = (blockIdx.x + 1) * CH; if (pend > nB) pend = nB;
  for (int p0 = blockIdx.x*CH + threadIdx.x; p0 < pend; p0 += 2*HBLOCK){
    const int p1 = p0 + HBLOCK;
    const bool has1 = p1 < pend;
    HPt h0, h1;
    hprep(xin, p0, res, sc, dense, h0);
    hprep(xin, has1 ? p1 : p0, res, sc, dense, h1);
    unsigned r0 = hgather(stab, h0);
    unsigned r1 = hgather(stab, h1);
    fout[p0] = r0;
    if (has1) fout[p1] = r1;
  }
}

// ---------------------------------------------------------------------------
// Phase B: register-chain MLP — no act LDS, no fences. 2 tiles/iter share A.
// ---------------------------------------------------------------------------
__global__ __launch_bounds__(BLOCK) void mlp_phase(
    const unsigned int* __restrict__ feat,
    const float* __restrict__ w1,  const float* __restrict__ b1,
    const float* __restrict__ w2,  const float* __restrict__ b2,
    const float* __restrict__ w3,  const float* __restrict__ b3,
    const float* __restrict__ cw1, const float* __restrict__ cb1,
    const float* __restrict__ cw2, const float* __restrict__ cb2,
    const float* __restrict__ cw3, const float* __restrict__ cb3,
    const float* __restrict__ cw4, const float* __restrict__ cb4,
    float* __restrict__ out, int nB)
{
  __shared__ __align__(16) unsigned short smem[SMEM_US];
  __shared__ __align__(16) unsigned short sbias[328];
  STAGE_ALL();
  __syncthreads();

  const int lane = threadIdx.x & 63, wv = threadIdx.x >> 6;
  const int q = lane >> 4, m = lane & 15;
  const unsigned int* fq = feat + (size_t)(4*q) * (size_t)nB;
  const float b3f = ubfu(sbias[NB_B3S]);

  for (int it = 0; it < 2; ++it){
    const int gp0 = blockIdx.x*BLOCK + wv*64 + it*32 + m;
    const int gp1 = gp0 + 16;
    const int gl0 = min(gp0, nB-1), gl1 = min(gp1, nB-1);
    union { u32x4 u; bf8 b; } fb0, fb1;
#pragma unroll
    for (int l = 0; l < 4; ++l){
      fb0.u[l] = fq[(size_t)nB*l + gl0];
      fb1.u[l] = fq[(size_t)nB*l + gl1];
    }
    bf8 x0b0, x0b1, x1b0, x1b1;
    layerL1_2(smem, sbias, fb0.b, fb1.b, lane, q, x0b0, x0b1, x1b0, x1b1);
    layer64_2(smem+OFF_W2,  sbias+NB_B2,  lane, q, x0b0, x0b1, x1b0, x1b1);
    sigma2(smem, b3f, lane, q, x0b0, x0b1, x1b0, x1b1, out, gp0, gp1, nB);
    layer64_2(smem+OFF_W3C, sbias+NB_BC,  lane, q, x0b0, x0b1, x1b0, x1b1);
    layer64_2(smem+OFF_CW2, sbias+NB_CB2, lane, q, x0b0, x0b1, x1b0, x1b1);
    layer64_2(smem+OFF_CW3, sbias+NB_CB3, lane, q, x0b0, x0b1, x1b0, x1b1);
    c4_2(smem, sbias, lane, q, x0b0, x0b1, x1b0, x1b1, out, gp0, gp1, nB);
  }
}

// ---------------------------------------------------------------------------
// Fallback (workspace too small): fused hash+MLP, single tile register chain.
// ---------------------------------------------------------------------------
__global__ __launch_bounds__(BLOCK) void nerf_fused(
    const float* __restrict__ xin, const float* __restrict__ tab,
    const float* __restrict__ w1,  const float* __restrict__ b1,
    const float* __restrict__ w2,  const float* __restrict__ b2,
    const float* __restrict__ w3,  const float* __restrict__ b3,
    const float* __restrict__ cw1, const float* __restrict__ cb1,
    const float* __restrict__ cw2, const float* __restrict__ cb2,
    const float* __restrict__ cw3, const float* __restrict__ cb3,
    const float* __restrict__ cw4, const float* __restrict__ cb4,
    float* __restrict__ out, int nB)
{
  __shared__ __align__(16) unsigned short smem[SMEM_US];
  __shared__ __align__(16) unsigned short sbias[328];
  STAGE_ALL();
  __syncthreads();

  const int lane = threadIdx.x & 63, wv = threadIdx.x >> 6;
  const int q = lane >> 4, m = lane & 15;
  const float b3f = ubfu(sbias[NB_B3S]);
  const int R[16] = {16,20,25,32,40,50,64,80,101,128,161,203,256,322,406,512};

  for (int it = 0; it < 2; ++it){
    const int gp0 = blockIdx.x*BLOCK + wv*64 + it*32 + m;
    const int gp1 = gp0 + 16;
    union { u32x4 u; bf8 b; } fb0, fb1;
#pragma unroll
    for (int half = 0; half < 2; ++half){
      const int gp = half ? gp1 : gp0;
      const int gpl = min(gp, nB-1);
      const float px = xin[gpl*3+0], py = xin[gpl*3+1], pz = xin[gpl*3+2];
#pragma unroll
      for (int d = 0; d < 4; ++d){
        const int lvl = 4*q + d;
        const int res = R[lvl];
        const float sc = 0.5f*(float)(res-1);
        const bool dense = (lvl < 3);
        HPt h;
        {
          const float xs=(px+1.f)*sc, ys=(py+1.f)*sc, zs=(pz+1.f)*sc;
          const float fx=floorf(xs), fy=floorf(ys), fz=floorf(zs);
          const float wx=xs-fx, wy=ys-fy, wz=zs-fz;
          int ix0=min(max((int)fx,0),res-1);
          int iy0=min(max((int)fy,0),res-1);
          int iz0=min(max((int)fz,0),res-1);
          int ix1=min(ix0+1,res-1), iy1=min(iy0+1,res-1), iz1=min(iz0+1,res-1);
          unsigned X0,X1,Y0,Y1,Z0,Z1;
          if (dense){
            X0=(unsigned)ix0;            X1=(unsigned)ix1;
            Y0=(unsigned)(res*iy0);      Y1=(unsigned)(res*iy1);
            Z0=(unsigned)(res*res*iz0);  Z1=(unsigned)(res*res*iz1);
          } else {
            X0=(unsigned)ix0;                 X1=(unsigned)ix1;
            Y0=(unsigned)iy0*2654435761u;     Y1=(unsigned)iy1*2654435761u;
            Z0=(unsigned)iz0*805459861u;      Z1=(unsigned)iz1*805459861u;
          }
          const float wx0=1.f-wx, wy0=1.f-wy, wz0=1.f-wz;
#pragma unroll
          for (int c = 0; c < 8; ++c){
            unsigned xc = (c&1)?X1:X0;
            unsigned yc = (c&2)?Y1:Y0;
            unsigned zc = (c&4)?Z1:Z0;
            h.idx[c] = dense ? (xc+yc+zc) : ((xc^yc^zc)&16383u);
            h.w[c] = ((c&1)?wx:wx0) * ((c&2)?wy:wy0) * ((c&4)?wz:wz0);
          }
        }
        const float2* tl = (const float2*)tab + (lvl<<14);
        float f0=0.f, f1=0.f;
#pragma unroll
        for (int c = 0; c < 8; ++c){
          float2 tv = tl[h.idx[c]];
          f0 = fmaf(h.w[c], tv.x, f0);
          f1 = fmaf(h.w[c], tv.y, f1);
        }
        unsigned pk = ((unsigned)f2bfu(f1) << 16) | (unsigned)f2bfu(f0);
        if (half) fb1.u[d] = pk; else fb0.u[d] = pk;
      }
    }
    bf8 x0b0, x0b1, x1b0, x1b1;
    layerL1_2(smem, sbias, fb0.b, fb1.b, lane, q, x0b0, x0b1, x1b0, x1b1);
    layer64_2(smem+OFF_W2,  sbias+NB_B2,  lane, q, x0b0, x0b1, x1b0, x1b1);
    sigma2(smem, b3f, lane, q, x0b0, x0b1, x1b0, x1b1, out, gp0, gp1, nB);
    layer64_2(smem+OFF_W3C, sbias+NB_BC,  lane, q, x0b0, x0b1, x1b0, x1b1);
    layer64_2(smem+OFF_CW2, sbias+NB_CB2, lane, q, x0b0, x0b1, x1b0, x1b1);
    layer64_2(smem+OFF_CW3, sbias+NB_CB3, lane, q, x0b0, x0b1, x1b0, x1b1);
    c4_2(smem, sbias, lane, q, x0b0, x0b1, x1b0, x1b1, out, gp0, gp1, nB);
  }
}

extern "C" void kernel_launch(void* const* d_in, const int* in_sizes, int n_in,
                              void* d_out, int out_size, void* d_ws, size_t ws_size,
                              hipStream_t stream) {
  (void)n_in; (void)out_size;
  const int nB = in_sizes[0] / 3;
  const float* xin = (const float*)d_in[0];
  const float* tab = (const float*)d_in[1];
  const float *w1=(const float*)d_in[2],  *b1=(const float*)d_in[3];
  const float *w2=(const float*)d_in[4],  *b2=(const float*)d_in[5];
  const float *w3=(const float*)d_in[6],  *b3=(const float*)d_in[7];
  const float *cw1=(const float*)d_in[8], *cb1=(const float*)d_in[9];
  const float *cw2=(const float*)d_in[10],*cb2=(const float*)d_in[11];
  const float *cw3=(const float*)d_in[12],*cb3=(const float*)d_in[13];
  const float *cw4=(const float*)d_in[14],*cb4=(const float*)d_in[15];
  float* out = (float*)d_out;

  const size_t need = (size_t)nB * 16u * 4u;
  if (ws_size >= need){
    unsigned int* feat = (unsigned int*)d_ws;
    dim3 ga((nB + CH - 1) / CH, 16);
    hash_phase<<<ga, dim3(HBLOCK), 0, stream>>>(xin, tab, feat, nB);
    const int blocks = (nB + BLOCK - 1) / BLOCK;
    mlp_phase<<<dim3(blocks), dim3(BLOCK), 0, stream>>>(
        feat, w1,b1,w2,b2,w3,b3,
        cw1,cb1,cw2,cb2,cw3,cb3,cw4,cb4, out, nB);
  } else {
    const int blocks = (nB + BLOCK - 1) / BLOCK;
    nerf_fused<<<dim3(blocks), dim3(BLOCK), 0, stream>>>(
        xin, tab, w1,b1,w2,b2,w3,b3,
        cw1,cb1,cw2,cb2,cw3,cb3,cw4,cb4, out, nB);
  }
}